// Round 4
// baseline (173.966 us; speedup 1.0000x reference)
//
#include <hip/hip_runtime.h>

typedef unsigned short u16;
typedef unsigned int u32;
typedef float v4f __attribute__((ext_vector_type(4)));
typedef __bf16 v8bf __attribute__((ext_vector_type(8)));

__device__ __forceinline__ u16 f2bf(float f) {
    union { float f; u32 u; } v; v.f = f;
    u32 r = v.u + 0x7fffu + ((v.u >> 16) & 1u);   // RNE
    return (u16)(r >> 16);
}
__device__ __forceinline__ u32 pk2(float lo, float hi) {
    return ((u32)f2bf(hi) << 16) | (u32)f2bf(lo);
}
// truncating pack of two f32 -> bf16x2 in ONE v_perm_b32
__device__ __forceinline__ u32 pk2t(float lo, float hi) {
    union { float f; u32 u; } a, b; a.f = hi; b.f = lo;
    return __builtin_amdgcn_perm(a.u, b.u, 0x07060302u);
}
__device__ __forceinline__ float bfLo(u32 p) {
    union { u32 u; float f; } v; v.u = p << 16; return v.f;
}
__device__ __forceinline__ float bfHi(u32 p) {
    union { u32 u; float f; } v; v.u = p & 0xffff0000u; return v.f;
}
__device__ __forceinline__ v4f zero4() { v4f z = {0.f, 0.f, 0.f, 0.f}; return z; }

#define AG_ST_U32(p, v) __hip_atomic_store((p), (v), __ATOMIC_RELAXED, __HIP_MEMORY_SCOPE_AGENT)
#define AG_ST_F32(p, v) __hip_atomic_store((p), (v), __ATOMIC_RELAXED, __HIP_MEMORY_SCOPE_AGENT)
#define AG_LD_I32(p)    __hip_atomic_load((p), __ATOMIC_RELAXED, __HIP_MEMORY_SCOPE_AGENT)
#define AG_LD_U32(p)    __hip_atomic_load((p), __ATOMIC_RELAXED, __HIP_MEMORY_SCOPE_AGENT)
#define AG_LD_F32(p)    __hip_atomic_load((p), __ATOMIC_RELAXED, __HIP_MEMORY_SCOPE_AGENT)
#define AG_ADD_I32(p)   __hip_atomic_fetch_add((p), 1, __ATOMIC_RELAXED, __HIP_MEMORY_SCOPE_AGENT)

// ---------------------------------------------------------------------------
// Kernel 0: zero the device-side ordering flags (re-poisoned every iteration).
// flags layout: [0,256) finalize counters | [256,512) tileReady | [512] prepDone
// ---------------------------------------------------------------------------
__global__ __launch_bounds__(64) void zero_flags(int* __restrict__ flags) {
#pragma unroll
    for (int i = 0; i < 9; ++i) {
        int idx = (int)threadIdx.x + i * 64;
        if (idx < 520) AG_ST_U32(&flags[idx], 0);
    }
}

// ---------------------------------------------------------------------------
// Kernel 1: FUSED prep_w + qkv_proj + attn(+combine). grid 512 x 256.
// 72 KB LDS + __launch_bounds__(256,2) => exactly 2 blocks/CU => ALL 512
// blocks co-resident => device-side spin-waits are deadlock-free.
// Ordering protocol (round-2-proven): producers write-through (relaxed agent
// stores -> coherent at memory-side cache, never any L2 flush), then
// vmcnt(0) + fabric atomicAdd on a flag; consumers spin on agent loads of the
// flag, then read the data with NORMAL cached loads (lines can never be stale:
// only write-through copies + kernel-boundary-flushed fill lines exist).
//   prep:  last 96 blocks convert W -> WtF frags, bump prepDone (target 96).
//   qkv:   all blocks, 32 token-rows each; after frag stores bump
//          tileReady[token-tile] (target 2: two 32-row blocks per 64-tile).
//   attn:  2176 units of (b, a, c), KC=4, MAXCH=16; each unit = one wave-pair;
//          pair p = blockIdx*2 + (wave>>1) takes units {p, p+1024, p+2048}.
//          Per-wave work is the round-2 attn body verbatim (no LDS, no sync).
//          cnt[b*64+a] counts WAVES (target 2*nch); last wave combines with
//          64 threads and writes out.
// ---------------------------------------------------------------------------
__global__ __launch_bounds__(256, 2) void fused_all(
    const float* __restrict__ x, const float* __restrict__ Wk,
    const float* __restrict__ Wq, const float* __restrict__ Wv,
    u16* __restrict__ WtF, u16* __restrict__ qgf, u16* __restrict__ Kf,
    u16* __restrict__ Vf, u32* __restrict__ Opb, float* __restrict__ ml,
    int* __restrict__ flags, float* __restrict__ out) {

    __shared__ v4f red[3][24][64];   // 72 KB; overlaid by T-tiles after reduce
    u16* Tk = (u16*)&red[0][0][0];   // [32][72]
    u16* Tq = Tk + 32 * 72;          // [32][72]
    u16* Tv = Tq + 32 * 72;          // [64][40]

    int* cnt       = flags;          // 256
    int* tileReady = flags + 256;    // 256
    int* prepDone  = flags + 512;    // 1

    const int tid  = threadIdx.x;
    const int lane = tid & 63;
    const int w4   = tid >> 6;       // wave index in block, 0..3
    const int beta = blockIdx.x;
    const int l15  = lane & 15, quad = lane >> 4;

    // ===================== prep phase (blocks 416..511) =====================
    if (beta >= 416) {
        const int ps = (beta - 416) * 4 + w4;           // [0,384)
        const int f = ps >> 5, ks = ps & 31;
        const int wsel = f >> 2;
        const float* W = (wsel == 0) ? Wk : ((wsel == 1) ? Wq : Wv);
        const int h = (f & 3) * 16 + l15;
        const int k0 = ks * 32 + quad * 8;
        union { u16 t[8]; u32 u[4]; } tmp;
#pragma unroll
        for (int j = 0; j < 8; ++j) tmp.t[j] = f2bf(W[(size_t)(k0 + j) * 64 + h]);
        u32* dst = (u32*)&WtF[((size_t)ps * 64 + lane) * 8];
#pragma unroll
        for (int j = 0; j < 4; ++j) AG_ST_U32(&dst[j], tmp.u[j]);
        asm volatile("s_waitcnt vmcnt(0)" ::: "memory");
        __syncthreads();
        if (tid == 0) AG_ADD_I32(prepDone);
    }

    // ===================== qkv phase (all blocks) =====================
    const int row0 = beta * 32;
    {
        v4f acc[2][12];
#pragma unroll
        for (int rh = 0; rh < 2; ++rh)
#pragma unroll
            for (int i = 0; i < 12; ++i) acc[rh][i] = zero4();

        // preload x slice: 32 float4/lane in 4 batches of 8 -> A-frags
        union { u32 u[4]; v8bf v; } af[2][8];
#pragma unroll
        for (int rh = 0; rh < 2; ++rh) {
            const float* xr = x + (size_t)(row0 + rh * 16 + l15) * 1024 + w4 * 256 + quad * 8;
#pragma unroll
            for (int half = 0; half < 2; ++half) {
                float4 t[8];
#pragma unroll
                for (int i = 0; i < 8; ++i)
                    t[i] = *(const float4*)(xr + half * 128 + (i >> 1) * 32 + (i & 1) * 4);
#pragma unroll
                for (int j = 0; j < 4; ++j) {
                    int ks = half * 4 + j;
                    af[rh][ks].u[0] = pk2(t[2 * j].x, t[2 * j].y);
                    af[rh][ks].u[1] = pk2(t[2 * j].z, t[2 * j].w);
                    af[rh][ks].u[2] = pk2(t[2 * j + 1].x, t[2 * j + 1].y);
                    af[rh][ks].u[3] = pk2(t[2 * j + 1].z, t[2 * j + 1].w);
                }
            }
        }

        // wait for WtF (prep) -- all 512 blocks co-resident, so safe
        while (AG_LD_I32(prepDone) < 96) __builtin_amdgcn_s_sleep(8);

        const u16* wf0 = WtF + ((size_t)(w4 * 8) * 64 + lane) * 8;
#pragma unroll
        for (int f = 0; f < 12; ++f) {
            const u16* wpf = wf0 + (size_t)f * 16384;
#pragma unroll
            for (int ks = 0; ks < 8; ++ks) {
                v8bf bw = *(const v8bf*)(wpf + ks * 512);
                acc[0][f] = __builtin_amdgcn_mfma_f32_16x16x32_bf16(af[0][ks].v, bw,
                                                                    acc[0][f], 0, 0, 0);
                acc[1][f] = __builtin_amdgcn_mfma_f32_16x16x32_bf16(af[1][ks].v, bw,
                                                                    acc[1][f], 0, 0, 0);
            }
        }

        if (w4 > 0) {
#pragma unroll
            for (int rh = 0; rh < 2; ++rh)
#pragma unroll
                for (int f = 0; f < 12; ++f) red[w4 - 1][rh * 12 + f][lane] = acc[rh][f];
        }
        __syncthreads();
        if (w4 == 0) {
#pragma unroll
            for (int rh = 0; rh < 2; ++rh)
#pragma unroll
                for (int f = 0; f < 12; ++f) {
                    acc[rh][f] += red[0][rh * 12 + f][lane];
                    acc[rh][f] += red[1][rh * 12 + f][lane];
                    acc[rh][f] += red[2][rh * 12 + f][lane];
                }
        }
        __syncthreads();   // all red reads done before T-tile overlay writes
        if (w4 == 0) {
            const float QSC = 0.04508422002778f;  // 2^-5 * log2(e)
#pragma unroll
            for (int rh = 0; rh < 2; ++rh)
#pragma unroll
                for (int ct = 0; ct < 4; ++ct)
#pragma unroll
                    for (int r = 0; r < 4; ++r) {
                        int tok = rh * 16 + quad * 4 + r;
                        Tk[tok * 72 + ct * 16 + l15] = f2bf(acc[rh][ct][r]);
                        Tq[tok * 72 + ct * 16 + l15] = f2bf(acc[rh][ct + 4][r] * QSC);
                        Tv[(ct * 16 + l15) * 40 + tok] = f2bf(acc[rh][ct + 8][r]);
                    }
        }
        __syncthreads();

        const int b = row0 >> 12, t0 = row0 & 4095;
        const int kt = t0 >> 6, ct0 = (t0 >> 4) & 3, ksv = (t0 >> 5) & 1;
        const int ln = tid & 63, l15p = ln & 15, qd = ln >> 4;

        // Q B-frag store (write-through u32 x4)
        {
            int gi = tid >> 7, fi = (tid >> 6) & 1;
            union { uint4 q; u32 u[4]; } v;
            v.q = *(const uint4*)&Tq[(gi * 16 + l15p) * 72 + fi * 32 + qd * 8];
            u32* dst = (u32*)&qgf[((size_t)((beta * 2 + gi) * 2 + fi) * 64 + ln) * 8];
#pragma unroll
            for (int j = 0; j < 4; ++j) AG_ST_U32(&dst[j], v.u[j]);
        }
        // Kf frag store
        {
            int cti = tid >> 7, ks = (tid >> 6) & 1;
            size_t fb = ((((size_t)(b * 64 + kt) * 4 + ct0 + cti) * 2 + ks) * 64 + ln) * 8;
            union { uint4 q; u32 u[4]; } v;
            v.q = *(const uint4*)&Tk[(cti * 16 + l15p) * 72 + ks * 32 + qd * 8];
            u32* dst = (u32*)&Kf[fb];
#pragma unroll
            for (int j = 0; j < 4; ++j) AG_ST_U32(&dst[j], v.u[j]);
        }
        // Vf frag store
        {
            int ht = tid >> 6;
            size_t fb = ((((size_t)(b * 64 + kt) * 4 + ht) * 2 + ksv) * 64 + ln) * 8;
            union { uint4 q; u32 u[4]; } v;
            v.q = *(const uint4*)&Tv[(ht * 16 + l15p) * 40 + qd * 8];
            u32* dst = (u32*)&Vf[fb];
#pragma unroll
            for (int j = 0; j < 4; ++j) AG_ST_U32(&dst[j], v.u[j]);
        }
        asm volatile("s_waitcnt vmcnt(0)" ::: "memory");
        __syncthreads();
        if (tid == 0) AG_ADD_I32(&tileReady[beta >> 1]);   // tile = 2 blocks
    }

    // ===================== attn phase =====================
    const int pib = w4 >> 1;     // pair-in-block (0,1)
    const int wvp = w4 & 1;      // wave-in-pair == old wv

    union { u32 u[4]; v8bf v; } ones;
    ones.u[0] = ones.u[1] = ones.u[2] = ones.u[3] = 0x3F803F80u;  // bf16 1.0 x8

    for (int u = beta * 2 + pib; u < 2176; u += 1024) {
        // ---- decode u (c-major enumeration, KC=4) -> (c, b, a) ----
        int cc = 0, uu = u, n = 256;
        while (uu >= n) { uu -= n; ++cc; n = (64 - 4 * cc) * 4; }
        const int span = 64 - 4 * cc;
        const int b = uu / span;
        const int a = 4 * cc + (uu - b * span);
        const int c = cc;
        const int kt0 = c * 4;
        const int kt1 = (kt0 + 4 < a + 1) ? (kt0 + 4) : (a + 1);
        const int nch = (a >> 2) + 1;

        // ---- wait for Q tile and K/V tiles ----
        {
            while (AG_LD_I32(&tileReady[b * 64 + a]) < 2) __builtin_amdgcn_s_sleep(2);
            for (int kt = kt1 - 1; kt >= kt0; --kt)
                while (AG_LD_I32(&tileReady[b * 64 + kt]) < 2) __builtin_amdgcn_s_sleep(2);
        }

        const int q0 = a * 64 + wvp * 32;
        const int g0 = (b * 4096 + q0) >> 4;
        v8bf qf[2][2];
#pragma unroll
        for (int st = 0; st < 2; ++st) {
#pragma unroll
            for (int f = 0; f < 2; ++f)
                qf[st][f] = *(const v8bf*)&qgf[((size_t)((g0 + st) * 2 + f) * 64 + lane) * 8];
        }

        v4f o[2][4], l5[2];
#pragma unroll
        for (int st = 0; st < 2; ++st) {
            l5[st] = zero4();
#pragma unroll
            for (int i = 0; i < 4; ++i) o[st][i] = zero4();
        }

        for (int kt = kt0; kt < kt1; ++kt) {
            const size_t tb = ((size_t)(b * 64 + kt) * 4) * 2 * 512;
            const u16* kp = Kf + tb + lane * 8;
            const u16* vp = Vf + tb + lane * 8;

            v8bf ka[4][2], av[4][2];
#pragma unroll
            for (int ct = 0; ct < 4; ++ct) {
                ka[ct][0] = *(const v8bf*)(kp + (ct * 2 + 0) * 512);
                ka[ct][1] = *(const v8bf*)(kp + (ct * 2 + 1) * 512);
                av[ct][0] = *(const v8bf*)(vp + (ct * 2 + 0) * 512);
                av[ct][1] = *(const v8bf*)(vp + (ct * 2 + 1) * 512);
            }

#pragma unroll
            for (int st = 0; st < 2; ++st) {
                v4f s[4];
#pragma unroll
                for (int ct = 0; ct < 4; ++ct) {
                    v4f t = zero4();
                    t = __builtin_amdgcn_mfma_f32_16x16x32_bf16(ka[ct][0], qf[st][0], t, 0, 0, 0);
                    t = __builtin_amdgcn_mfma_f32_16x16x32_bf16(ka[ct][1], qf[st][1], t, 0, 0, 0);
                    s[ct] = t;
                }

                if (kt == a) {   // causal mask only on the diagonal tile
                    const int queryg = q0 + st * 16 + l15;
                    const int key0 = kt * 64 + quad * 4;
#pragma unroll
                    for (int ct = 0; ct < 4; ++ct)
#pragma unroll
                        for (int r = 0; r < 4; ++r)
                            s[ct][r] = ((key0 + ct * 16 + r) > queryg) ? -1e30f : s[ct][r];
                }

                u32 pk[4][2];
#pragma unroll
                for (int ct = 0; ct < 4; ++ct) {
                    float p0 = exp2f(s[ct][0]);
                    float p1 = exp2f(s[ct][1]);
                    float p2 = exp2f(s[ct][2]);
                    float p3 = exp2f(s[ct][3]);
                    pk[ct][0] = pk2t(p0, p1);
                    pk[ct][1] = pk2t(p2, p3);
                }

                const int srcA = ((quad & 1) << 5) + l15;
                const int srcB = srcA + 16;
                const bool hi = (quad >= 2);
#pragma unroll
                for (int ks = 0; ks < 2; ++ks) {
                    u32 g0a = (u32)__shfl((int)pk[ks * 2][0], srcA);
                    u32 g0b = (u32)__shfl((int)pk[ks * 2 + 1][0], srcA);
                    u32 g1a = (u32)__shfl((int)pk[ks * 2][1], srcA);
                    u32 g1b = (u32)__shfl((int)pk[ks * 2 + 1][1], srcA);
                    u32 g2a = (u32)__shfl((int)pk[ks * 2][0], srcB);
                    u32 g2b = (u32)__shfl((int)pk[ks * 2 + 1][0], srcB);
                    u32 g3a = (u32)__shfl((int)pk[ks * 2][1], srcB);
                    u32 g3b = (u32)__shfl((int)pk[ks * 2 + 1][1], srcB);
                    union { u32 u[4]; v8bf v; } pf;
                    pf.u[0] = hi ? g0b : g0a;
                    pf.u[1] = hi ? g1b : g1a;
                    pf.u[2] = hi ? g2b : g2a;
                    pf.u[3] = hi ? g3b : g3a;
#pragma unroll
                    for (int ht = 0; ht < 4; ++ht)
                        o[st][ht] = __builtin_amdgcn_mfma_f32_16x16x32_bf16(
                            av[ht][ks], pf.v, o[st][ht], 0, 0, 0);
                    l5[st] = __builtin_amdgcn_mfma_f32_16x16x32_bf16(
                        ones.v, pf.v, l5[st], 0, 0, 0);
                }
            }
        }

        const size_t pbase = ((size_t)b * 64 + a) * 16;   // MAXCH=16
        const size_t pidx = pbase + c;
        u32* op = Opb + pidx * 2048;
#pragma unroll
        for (int st = 0; st < 2; ++st) {
#pragma unroll
            for (int ht = 0; ht < 2; ++ht)
#pragma unroll
                for (int r = 0; r < 4; ++r)
                    AG_ST_U32(&op[(ht * 16 + quad * 4 + r) * 64 + wvp * 32 + st * 16 + l15],
                              pk2t(o[st][ht][r], o[st][ht + 2][r]));
            if (quad == 0)
                AG_ST_F32(&ml[pidx * 64 + wvp * 32 + st * 16 + l15], l5[st][0]);
        }

        asm volatile("s_waitcnt vmcnt(0)" ::: "memory");
        int old = 0;
        if (lane == 0) old = AG_ADD_I32(&cnt[b * 64 + a]);
        old = __shfl(old, 0);

        if (old == 2 * nch - 1) {
            // ---- last wave combines (64 threads: q = lane) ----
            const int q = lane;
            float L = 0.f;
            float accL[32], accH[32];
#pragma unroll
            for (int j = 0; j < 32; ++j) { accL[j] = 0.f; accH[j] = 0.f; }
            for (int ch = 0; ch < nch; ++ch) {
                L += AG_LD_F32(&ml[(pbase + ch) * 64 + q]);
                const u32* op2 = Opb + (pbase + ch) * 2048;
#pragma unroll
                for (int r = 0; r < 32; ++r) {
                    u32 v = AG_LD_U32(&op2[r * 64 + q]);
                    accL[r] += bfLo(v);
                    accH[r] += bfHi(v);
                }
            }
            const float inv = 1.f / L;
            float* orow = out + ((size_t)b * 4096 + a * 64 + q) * 64;
#pragma unroll
            for (int j4 = 0; j4 < 8; ++j4) {
                float4 lo4 = {accL[4 * j4] * inv, accL[4 * j4 + 1] * inv,
                              accL[4 * j4 + 2] * inv, accL[4 * j4 + 3] * inv};
                float4 hi4 = {accH[4 * j4] * inv, accH[4 * j4 + 1] * inv,
                              accH[4 * j4 + 2] * inv, accH[4 * j4 + 3] * inv};
                *(float4*)&orow[4 * j4] = lo4;          // h in [0,32)
                *(float4*)&orow[32 + 4 * j4] = hi4;     // h in [32,64)
            }
        }
    }
}

// ---------------------------------------------------------------------------
extern "C" void kernel_launch(void* const* d_in, const int* in_sizes, int n_in,
                              void* d_out, int out_size, void* d_ws, size_t ws_size,
                              hipStream_t stream) {
    const float* x  = (const float*)d_in[0];
    const float* Wk = (const float*)d_in[1];
    const float* Wq = (const float*)d_in[2];
    const float* Wv = (const float*)d_in[3];
    float* out = (float*)d_out;

    char* wsb = (char*)d_ws;
    u16* WtF = (u16*)wsb;                                  // 393216 B
    u16* qgf = (u16*)(wsb + 393216);                       // 2 MiB
    u16* Kf  = (u16*)(wsb + 393216 + 2097152);             // 2 MiB
    u16* Vf  = (u16*)(wsb + 393216 + 2 * 2097152);         // 2 MiB
    const size_t base = 393216 + 3 * 2097152;              // 6684672
    // KC=4, MAXCH=16 hardcoded (ws has been 256 MiB every round; need 41.3 MB)
    u32* Opb   = (u32*)(wsb + base);                       // 32 MiB
    float* mlp = (float*)(wsb + base + (size_t)256 * 16 * 2048 * 4);   // 1 MiB
    int* flags = (int*)(wsb + base + (size_t)256 * 16 * 2048 * 4 + 1048576);

    zero_flags<<<dim3(1), dim3(64), 0, stream>>>(flags);
    fused_all<<<dim3(512), dim3(256), 0, stream>>>(x, Wk, Wq, Wv, WtF, qgf, Kf, Vf,
                                                   Opb, mlp, flags, out);
}

// Round 5
// 137.690 us; speedup vs baseline: 1.2635x; 1.2635x over previous
//
#include <hip/hip_runtime.h>

typedef unsigned short u16;
typedef unsigned int u32;
typedef float v4f __attribute__((ext_vector_type(4)));
typedef __bf16 v8bf __attribute__((ext_vector_type(8)));

__device__ __forceinline__ u16 f2bf(float f) {
    union { float f; u32 u; } v; v.f = f;
    u32 r = v.u + 0x7fffu + ((v.u >> 16) & 1u);   // RNE
    return (u16)(r >> 16);
}
__device__ __forceinline__ u32 pk2(float lo, float hi) {
    return ((u32)f2bf(hi) << 16) | (u32)f2bf(lo);
}
// truncating pack of two f32 -> bf16x2 in ONE v_perm_b32
__device__ __forceinline__ u32 pk2t(float lo, float hi) {
    union { float f; u32 u; } a, b; a.f = hi; b.f = lo;
    return __builtin_amdgcn_perm(a.u, b.u, 0x07060302u);
}
__device__ __forceinline__ float bfLo(u32 p) {
    union { u32 u; float f; } v; v.u = p << 16; return v.f;
}
__device__ __forceinline__ float bfHi(u32 p) {
    union { u32 u; float f; } v; v.u = p & 0xffff0000u; return v.f;
}
__device__ __forceinline__ v4f zero4() { v4f z = {0.f, 0.f, 0.f, 0.f}; return z; }

// ---------------------------------------------------------------------------
// Kernel 0: W[k][h] fp32 -> WtF fragment layout (1 KB frags). grid 384, blk 64
// ---------------------------------------------------------------------------
__global__ __launch_bounds__(64) void prep_w(const float* __restrict__ Wk,
                                             const float* __restrict__ Wq,
                                             const float* __restrict__ Wv,
                                             u16* __restrict__ WtF) {
    const int f = blockIdx.x >> 5;
    const int ks = blockIdx.x & 31;
    const int lane = threadIdx.x;
    const int w = f >> 2;
    const float* W = (w == 0) ? Wk : ((w == 1) ? Wq : Wv);
    const int h = (f & 3) * 16 + (lane & 15);
    const int k0 = ks * 32 + (lane >> 4) * 8;
    u16 tmp[8];
#pragma unroll
    for (int j = 0; j < 8; ++j) tmp[j] = f2bf(W[(size_t)(k0 + j) * 64 + h]);
    *(uint4*)&WtF[((size_t)blockIdx.x * 64 + lane) * 8] = *(const uint4*)tmp;
}

// ---------------------------------------------------------------------------
// Kernel 1: qkv projection. 32-row blocks; wave wv covers K [wv*256,+256).
// NEW vs round-0: the cross-wave reduce + f2bf conversion is statically
// partitioned across all 4 waves (slot s = rh*12+f, owner = s/6) instead of
// wave 0 doing all 24 slots serially. All acc[][] indices stay compile-time
// (runtime-indexed ext_vector arrays would spill to scratch).
// grid 512, block 256, 72 KB LDS, 2 blocks/CU
// ---------------------------------------------------------------------------
__global__ __launch_bounds__(256, 2) void qkv_proj(const float* __restrict__ x,
                                                   const u16* __restrict__ WtF,
                                                   u16* __restrict__ qgf,
                                                   u16* __restrict__ Kf,
                                                   u16* __restrict__ Vf) {
    __shared__ v4f red[24][3][64];   // 72 KB, slot-major; overlaid by T-tiles
    u16* Tk = (u16*)&red[0][0][0];   // [32][72]
    u16* Tq = Tk + 32 * 72;          // [32][72]
    u16* Tv = Tq + 32 * 72;          // [64][40]  (h-major, 32 tokens + pad)

    const int tid = threadIdx.x;
    const int lane = tid & 63;
    const int wv = tid >> 6;
    const int l15 = lane & 15, quad = lane >> 4;
    const int row0 = blockIdx.x * 32;

    v4f acc[2][12];
#pragma unroll
    for (int rh = 0; rh < 2; ++rh)
#pragma unroll
        for (int i = 0; i < 12; ++i) acc[rh][i] = zero4();

    // preload x slice: 32 float4/lane in 4 batches of 8, convert to A-frags
    union { u32 u[4]; v8bf v; } af[2][8];
#pragma unroll
    for (int rh = 0; rh < 2; ++rh) {
        const float* xr = x + (size_t)(row0 + rh * 16 + l15) * 1024 + wv * 256 + quad * 8;
#pragma unroll
        for (int half = 0; half < 2; ++half) {
            float4 t[8];
#pragma unroll
            for (int i = 0; i < 8; ++i)
                t[i] = *(const float4*)(xr + half * 128 + (i >> 1) * 32 + (i & 1) * 4);
#pragma unroll
            for (int j = 0; j < 4; ++j) {
                int ks = half * 4 + j;
                af[rh][ks].u[0] = pk2(t[2 * j].x, t[2 * j].y);
                af[rh][ks].u[1] = pk2(t[2 * j].z, t[2 * j].w);
                af[rh][ks].u[2] = pk2(t[2 * j + 1].x, t[2 * j + 1].y);
                af[rh][ks].u[3] = pk2(t[2 * j + 1].z, t[2 * j + 1].w);
            }
        }
    }

    const u16* wf0 = WtF + ((size_t)(wv * 8) * 64 + lane) * 8;
#pragma unroll
    for (int f = 0; f < 12; ++f) {
        const u16* wpf = wf0 + (size_t)f * 16384;
#pragma unroll
        for (int ks = 0; ks < 8; ++ks) {
            v8bf bw = *(const v8bf*)(wpf + ks * 512);
            acc[0][f] = __builtin_amdgcn_mfma_f32_16x16x32_bf16(af[0][ks].v, bw,
                                                                acc[0][f], 0, 0, 0);
            acc[1][f] = __builtin_amdgcn_mfma_f32_16x16x32_bf16(af[1][ks].v, bw,
                                                                acc[1][f], 0, 0, 0);
        }
    }

    // ---- slot-parallel reduce: slot s=rh*12+f, owner wave = s/6 ----
    // non-owners write their acc for s; owners keep theirs in registers
#pragma unroll
    for (int rh = 0; rh < 2; ++rh)
#pragma unroll
        for (int f = 0; f < 12; ++f) {
            const int s = rh * 12 + f;        // compile-time
            const int own = s / 6;            // compile-time
            if (own != wv) {
                int idx = (wv > own) ? (wv - 1) : wv;   // runtime LDS addr ok
                red[s][idx][lane] = acc[rh][f];
            }
        }
    __syncthreads();
#pragma unroll
    for (int rh = 0; rh < 2; ++rh)
#pragma unroll
        for (int f = 0; f < 12; ++f) {
            const int s = rh * 12 + f;
            if (s / 6 == wv) {
                acc[rh][f] += red[s][0][lane];
                acc[rh][f] += red[s][1][lane];
                acc[rh][f] += red[s][2][lane];
            }
        }
    __syncthreads();   // all red reads done before T-tile overlay writes

    // ---- slot-parallel conversion to T tiles ----
    {
        const float QSC = 0.04508422002778f;  // 2^-5 * log2(e)
#pragma unroll
        for (int rh = 0; rh < 2; ++rh)
#pragma unroll
            for (int f = 0; f < 12; ++f) {
                const int s = rh * 12 + f;
                if (s / 6 == wv) {
                    const int ct = f & 3;
#pragma unroll
                    for (int r = 0; r < 4; ++r) {
                        const int tok = rh * 16 + quad * 4 + r;
                        if (f < 4)
                            Tk[tok * 72 + ct * 16 + l15] = f2bf(acc[rh][f][r]);
                        else if (f < 8)
                            Tq[tok * 72 + ct * 16 + l15] = f2bf(acc[rh][f][r] * QSC);
                        else
                            Tv[(ct * 16 + l15) * 40 + tok] = f2bf(acc[rh][f][r]);
                    }
                }
            }
    }
    __syncthreads();

    const int b = row0 >> 12, t0 = row0 & 4095;
    const int kt = t0 >> 6, ct0 = (t0 >> 4) & 3, ksv = (t0 >> 5) & 1;
    const int ln = tid & 63, l15p = ln & 15, qd = ln >> 4;

    // Q B-frag store (4 KB): gi = token-16 group, fi = frag
    {
        int gi = tid >> 7, fi = (tid >> 6) & 1;
        *(uint4*)&qgf[((size_t)((blockIdx.x * 2 + gi) * 2 + fi) * 64 + ln) * 8] =
            *(const uint4*)&Tq[(gi * 16 + l15p) * 72 + fi * 32 + qd * 8];
    }
    // Kf frag store (4 KB): 2 ct x 2 ks frags
    {
        int cti = tid >> 7, ks = (tid >> 6) & 1;
        size_t fb = ((((size_t)(b * 64 + kt) * 4 + ct0 + cti) * 2 + ks) * 64 + ln) * 8;
        *(uint4*)&Kf[fb] = *(const uint4*)&Tk[(cti * 16 + l15p) * 72 + ks * 32 + qd * 8];
    }
    // Vf frag store (4 KB): 4 ht frags (full 32-key half ksv)
    {
        int ht = tid >> 6;
        size_t fb = ((((size_t)(b * 64 + kt) * 4 + ht) * 2 + ksv) * 64 + ln) * 8;
        *(uint4*)&Vf[fb] = *(const uint4*)&Tv[(ht * 16 + l15p) * 40 + qd * 8];
    }
}

// ---------------------------------------------------------------------------
// Kernel 2: attention partials. ZERO LDS, zero barriers; ALL loads (Q/K/V)
// are coalesced 1 KB frag loads. l_i via ones-MFMA. NO-MAX softmax.
// Partials stored bf16-packed (h, h+32) per u32. KC=8 (was 4): half the
// split-k units and half the partial traffic; each unit <= 8 kt tiles.
// grid (64 qtiles, MAXCH, 4 batch), block 128 (2 waves x 32 queries)
// ---------------------------------------------------------------------------
__global__ __launch_bounds__(128, 3) void attn_part(const u16* __restrict__ qgf,
                                                    const u16* __restrict__ Kf,
                                                    const u16* __restrict__ Vf,
                                                    u32* __restrict__ Opb,
                                                    float* __restrict__ ml,
                                                    int KC, int MAXCH) {
    const int a = blockIdx.x, c = blockIdx.y, b = blockIdx.z;
    if (c * KC > a) return;

    const int tid  = threadIdx.x;
    const int lane = tid & 63;
    const int wv   = tid >> 6;
    const int l15  = lane & 15;
    const int quad = lane >> 4;
    const int q0   = a * 64 + wv * 32;

    const int g0 = (b * 4096 + q0) >> 4;
    v8bf qf[2][2];
#pragma unroll
    for (int st = 0; st < 2; ++st) {
#pragma unroll
        for (int f = 0; f < 2; ++f)
            qf[st][f] = *(const v8bf*)&qgf[((size_t)((g0 + st) * 2 + f) * 64 + lane) * 8];
    }

    union { u32 u[4]; v8bf v; } ones;
    ones.u[0] = ones.u[1] = ones.u[2] = ones.u[3] = 0x3F803F80u;  // bf16 1.0 x8

    v4f o[2][4], l5[2];
#pragma unroll
    for (int st = 0; st < 2; ++st) {
        l5[st] = zero4();
#pragma unroll
        for (int i = 0; i < 4; ++i) o[st][i] = zero4();
    }

    const int kt0 = c * KC;
    const int kt1 = (kt0 + KC < a + 1) ? (kt0 + KC) : (a + 1);

    for (int kt = kt0; kt < kt1; ++kt) {
        const size_t tb = ((size_t)(b * 64 + kt) * 4) * 2 * 512;
        const u16* kp = Kf + tb + lane * 8;
        const u16* vp = Vf + tb + lane * 8;

        v8bf ka[4][2], av[4][2];
#pragma unroll
        for (int ct = 0; ct < 4; ++ct) {
            ka[ct][0] = *(const v8bf*)(kp + (ct * 2 + 0) * 512);
            ka[ct][1] = *(const v8bf*)(kp + (ct * 2 + 1) * 512);
            av[ct][0] = *(const v8bf*)(vp + (ct * 2 + 0) * 512);
            av[ct][1] = *(const v8bf*)(vp + (ct * 2 + 1) * 512);
        }

#pragma unroll
        for (int st = 0; st < 2; ++st) {
            v4f s[4];
#pragma unroll
            for (int ct = 0; ct < 4; ++ct) {
                v4f t = zero4();
                t = __builtin_amdgcn_mfma_f32_16x16x32_bf16(ka[ct][0], qf[st][0], t, 0, 0, 0);
                t = __builtin_amdgcn_mfma_f32_16x16x32_bf16(ka[ct][1], qf[st][1], t, 0, 0, 0);
                s[ct] = t;
            }

            if (kt == a) {   // causal mask only on the diagonal tile
                const int queryg = q0 + st * 16 + l15;
                const int key0 = kt * 64 + quad * 4;
#pragma unroll
                for (int ct = 0; ct < 4; ++ct)
#pragma unroll
                    for (int r = 0; r < 4; ++r)
                        s[ct][r] = ((key0 + ct * 16 + r) > queryg) ? -1e30f : s[ct][r];
            }

            u32 pk[4][2];
#pragma unroll
            for (int ct = 0; ct < 4; ++ct) {
                float p0 = exp2f(s[ct][0]);
                float p1 = exp2f(s[ct][1]);
                float p2 = exp2f(s[ct][2]);
                float p3 = exp2f(s[ct][3]);
                pk[ct][0] = pk2t(p0, p1);
                pk[ct][1] = pk2t(p2, p3);
            }

            const int srcA = ((quad & 1) << 5) + l15;
            const int srcB = srcA + 16;
            const bool hi = (quad >= 2);
#pragma unroll
            for (int ks = 0; ks < 2; ++ks) {
                u32 g0a = (u32)__shfl((int)pk[ks * 2][0], srcA);
                u32 g0b = (u32)__shfl((int)pk[ks * 2 + 1][0], srcA);
                u32 g1a = (u32)__shfl((int)pk[ks * 2][1], srcA);
                u32 g1b = (u32)__shfl((int)pk[ks * 2 + 1][1], srcA);
                u32 g2a = (u32)__shfl((int)pk[ks * 2][0], srcB);
                u32 g2b = (u32)__shfl((int)pk[ks * 2 + 1][0], srcB);
                u32 g3a = (u32)__shfl((int)pk[ks * 2][1], srcB);
                u32 g3b = (u32)__shfl((int)pk[ks * 2 + 1][1], srcB);
                union { u32 u[4]; v8bf v; } pf;
                pf.u[0] = hi ? g0b : g0a;
                pf.u[1] = hi ? g1b : g1a;
                pf.u[2] = hi ? g2b : g2a;
                pf.u[3] = hi ? g3b : g3a;
#pragma unroll
                for (int ht = 0; ht < 4; ++ht)
                    o[st][ht] = __builtin_amdgcn_mfma_f32_16x16x32_bf16(
                        av[ht][ks], pf.v, o[st][ht], 0, 0, 0);
                l5[st] = __builtin_amdgcn_mfma_f32_16x16x32_bf16(
                    ones.v, pf.v, l5[st], 0, 0, 0);
            }
        }
    }

    size_t pidx = ((size_t)b * 64 + a) * MAXCH + c;
    u32* op = Opb + pidx * 2048;
#pragma unroll
    for (int st = 0; st < 2; ++st) {
#pragma unroll
        for (int ht = 0; ht < 2; ++ht)
#pragma unroll
            for (int r = 0; r < 4; ++r)
                op[(ht * 16 + quad * 4 + r) * 64 + wv * 32 + st * 16 + l15] =
                    pk2t(o[st][ht][r], o[st][ht + 2][r]);
        if (quad == 0)
            ml[pidx * 64 + wv * 32 + st * 16 + l15] = l5[st][0];
    }
}

// ---------------------------------------------------------------------------
// Kernel 3: combine bf16-packed partials. grid (64, 4, 4), block 256;
// thread = (query=tid&63, h0 = hz*16 + (tid>>6)*4).
// ---------------------------------------------------------------------------
__global__ __launch_bounds__(256) void attn_combine(const u32* __restrict__ Opb,
                                                    const float* __restrict__ ml,
                                                    float* __restrict__ out,
                                                    int KC, int MAXCH) {
    const int a = blockIdx.x, b = blockIdx.y, hz = blockIdx.z;
    const int nch = a / KC + 1;
    const int tid = threadIdx.x;
    const int q = tid & 63, hq = tid >> 6;
    const int h0 = hz * 16 + hq * 4;
    const int rb = h0 & 31;
    const bool hi = (h0 >= 32);
    const size_t pbase = ((size_t)b * 64 + a) * MAXCH;

    float L = 0.f;
    float acc[4] = {0.f, 0.f, 0.f, 0.f};
    for (int c = 0; c < nch; ++c) {
        L += ml[(pbase + c) * 64 + q];
        const u32* op = Opb + (pbase + c) * 2048;
#pragma unroll
        for (int j = 0; j < 4; ++j) {
            u32 v = op[(rb + j) * 64 + q];
            acc[j] += hi ? bfHi(v) : bfLo(v);
        }
    }
    float inv = 1.f / L;
    float4 st = {acc[0] * inv, acc[1] * inv, acc[2] * inv, acc[3] * inv};
    *(float4*)&out[((size_t)b * 4096 + a * 64 + q) * 64 + h0] = st;
}

// ---------------------------------------------------------------------------
extern "C" void kernel_launch(void* const* d_in, const int* in_sizes, int n_in,
                              void* d_out, int out_size, void* d_ws, size_t ws_size,
                              hipStream_t stream) {
    const float* x  = (const float*)d_in[0];
    const float* Wk = (const float*)d_in[1];
    const float* Wq = (const float*)d_in[2];
    const float* Wv = (const float*)d_in[3];
    float* out = (float*)d_out;

    char* wsb = (char*)d_ws;
    u16* WtF = (u16*)wsb;                                  // 393216 B
    u16* qgf = (u16*)(wsb + 393216);                       // 2 MiB
    u16* Kf  = (u16*)(wsb + 393216 + 2097152);             // 2 MiB
    u16* Vf  = (u16*)(wsb + 393216 + 2 * 2097152);         // 2 MiB
    const size_t base = 393216 + 3 * 2097152;              // 6684672

    int KC = 8, MAXCH = 8;
    while (KC < 64 && base + (size_t)256 * MAXCH * (2048 * 4 + 256) > ws_size) {
        KC <<= 1; MAXCH >>= 1;
    }
    u32* Opb = (u32*)(wsb + base);
    float* ml = (float*)(wsb + base + (size_t)256 * MAXCH * 2048 * 4);

    prep_w<<<dim3(384), dim3(64), 0, stream>>>(Wk, Wq, Wv, WtF);
    qkv_proj<<<dim3(512), dim3(256), 0, stream>>>(x, WtF, qgf, Kf, Vf);
    attn_part<<<dim3(64, MAXCH, 4), dim3(128), 0, stream>>>(qgf, Kf, Vf, Opb, ml, KC, MAXCH);
    attn_combine<<<dim3(64, 4, 4), dim3(256), 0, stream>>>(Opb, ml, out, KC, MAXCH);
}